// Round 5
// baseline (715.889 us; speedup 1.0000x reference)
//
#include <hip/hip_runtime.h>
#include <hip/hip_bf16.h>

#define T_TOK 2048
#define H_DIM 2048
#define E_NUM 32
#define I_DIM 768
#define TOPK  4

typedef __attribute__((ext_vector_type(8))) short bf16x8;
typedef __attribute__((ext_vector_type(4))) float f32x4;

__device__ __forceinline__ unsigned pk2(float a, float b) {
    __hip_bfloat16 ha = __float2bfloat16(a);
    __hip_bfloat16 hb = __float2bfloat16(b);
    unsigned short ua = *(unsigned short*)&ha;
    unsigned short ub = *(unsigned short*)&hb;
    return (unsigned)ua | ((unsigned)ub << 16);
}

__device__ __forceinline__ void gld16(const void* g, void* l) {
    __builtin_amdgcn_global_load_lds(
        (const __attribute__((address_space(1))) void*)g,
        (__attribute__((address_space(3))) void*)l, 16, 0, 0);
}

#define SB0() __builtin_amdgcn_sched_barrier(0)
// publish barrier: my ds_writes visible (lgkmcnt 0), my staging loads for the
// buffer being published complete (vmcnt VM), then s_barrier.
#define WAITB(VM) do { SB0(); \
  asm volatile("s_waitcnt lgkmcnt(0)\n\ts_waitcnt vmcnt(%0)" :: "n"(VM) : "memory"); \
  SB0(); __builtin_amdgcn_s_barrier(); SB0(); } while (0)

// ---------------- Router ----------------
__global__ __launch_bounds__(64) void router_kernel(
    const float* __restrict__ x, const float* __restrict__ gate_w,
    float* __restrict__ logits_out, int* __restrict__ cnt,
    int* __restrict__ tok_list, float* __restrict__ tok_w)
{
    const int t = blockIdx.x;
    const int lane = threadIdx.x;
    __shared__ float xs[H_DIM];
    const float4* __restrict__ xv = (const float4*)(x + (size_t)t * H_DIM);
    float4* xsv = (float4*)xs;
#pragma unroll
    for (int i = 0; i < H_DIM / 4 / 64; ++i) xsv[lane + i * 64] = xv[lane + i * 64];
    __syncthreads();

    const int e = lane & 31;
    const int half = lane >> 5;
    const float4* __restrict__ wv = (const float4*)(gate_w + (size_t)e * H_DIM) + half * (H_DIM / 8);
    const float4* __restrict__ xh = ((const float4*)xs) + half * (H_DIM / 8);
    float acc = 0.f;
#pragma unroll 4
    for (int i = 0; i < H_DIM / 8; ++i) {
        float4 w4 = wv[i], x4 = xh[i];
        acc += w4.x * x4.x + w4.y * x4.y + w4.z * x4.z + w4.w * x4.w;
    }
    acc += __shfl_xor(acc, 32, 64);
    if (lane < 32) logits_out[(size_t)t * E_NUM + e] = acc;

    float v = acc;
    float topv[TOPK]; int topi[TOPK];
#pragma unroll
    for (int r = 0; r < TOPK; ++r) {
        float bv = v; int bi = e;
#pragma unroll
        for (int off = 16; off >= 1; off >>= 1) {
            float ov = __shfl_xor(bv, off, 32);
            int   oi = __shfl_xor(bi, off, 32);
            if (ov > bv || (ov == bv && oi < bi)) { bv = ov; bi = oi; }
        }
        topv[r] = bv; topi[r] = bi;
        if (e == bi) v = -1e30f;
    }
    if (lane == 0) {
        float w[TOPK]; float s = 0.f;
#pragma unroll
        for (int r = 0; r < TOPK; ++r) { w[r] = expf(topv[r] - topv[0]); s += w[r]; }
        float inv = 1.f / s;
#pragma unroll
        for (int r = 0; r < TOPK; ++r) {
            int pos = atomicAdd(&cnt[topi[r]], 1);
            tok_list[topi[r] * T_TOK + pos] = t;
            tok_w  [topi[r] * T_TOK + pos] = w[r] * inv;
        }
    }
}

__global__ void scan_kernel(const int* __restrict__ cnt, int* __restrict__ slot_base)
{
    if (threadIdx.x == 0) {
        int s = 0;
        for (int e = 0; e < E_NUM; ++e) { slot_base[e] = s; s += cnt[e]; }
        slot_base[E_NUM] = s;
    }
}

// ---------------- Gather tokens per expert, convert x -> bf16 ----------------
__global__ __launch_bounds__(256) void gather_kernel(
    const float* __restrict__ x, const int* __restrict__ cnt,
    const int* __restrict__ slot_base, const int* __restrict__ tok_list,
    unsigned short* __restrict__ xg)
{
    const int e = blockIdx.y;
    const int count = cnt[e];
    const int m0 = blockIdx.x * 16;
    if (m0 >= count) return;
    const int r = threadIdx.x >> 4;
    const int m = m0 + r;
    if (m >= count) return;
    const int tok  = tok_list[e * T_TOK + m];
    const int slot = slot_base[e] + m;
    const float* __restrict__ src = x + (size_t)tok * H_DIM;
    unsigned short* __restrict__ dst = xg + (size_t)slot * H_DIM;
    for (int c = (threadIdx.x & 15) * 4; c < H_DIM; c += 64) {
        float4 v = *(const float4*)(src + c);
        *(unsigned*)(dst + c)     = pk2(v.x, v.y);
        *(unsigned*)(dst + c + 2) = pk2(v.z, v.w);
    }
}

// ---------------- gate_up MFMA + silu + weight-scale -> h (bf16) ----------------
// tile 256(M) x 64(h), BK=32, 8 waves; counted-vmcnt pipeline:
// A: gld16 depth-1, 2 bufs.  B: reg-prefetch depth-3 (3 sets), ds_write 1 ahead, 3 bufs.
// per step issue order: [A(k+1) x2, B(k+3) x8] -> steady publish wait = vmcnt(8).
__global__ __launch_bounds__(512, 2) void gateup_mfma(
    const unsigned short* __restrict__ xg, const float* __restrict__ gup_w,
    const int* __restrict__ cnt, const int* __restrict__ slot_base,
    const float* __restrict__ tok_w, unsigned short* __restrict__ h_buf)
{
    const int e  = blockIdx.z;
    const int mt = blockIdx.y;
    const int nt = blockIdx.x;
    const int count = cnt[e];
    if (mt * 256 >= count) return;
    const int tid  = threadIdx.x;
    const int lane = tid & 63;
    const int w    = tid >> 6;
    const int wm   = w >> 1;
    const int wn   = w & 1;
    const int base = slot_base[e];
    const int l16  = lane & 15, lg = lane >> 4;

    __shared__ unsigned short As[2][4 * 256 * 8];   // 32 KB
    __shared__ unsigned short Bg[3][4 * 64 * 8];    // 12 KB
    __shared__ unsigned short Bu[3][4 * 64 * 8];    // 12 KB
    __shared__ float wls[256];                      //  1 KB

    if (tid < 256) {
        int m = mt * 256 + tid; if (m >= count) m = count - 1;
        wls[tid] = tok_w[e * T_TOK + m];
    }
    asm volatile("s_waitcnt vmcnt(0) lgkmcnt(0)" ::: "memory");
    SB0();

    // A staging addresses (wave-uniform LDS base + lane*16)
    const int kc = w >> 1;
    const int q0 = (w & 1) * 2;
    int r0 = mt * 256 + q0 * 64 + lane;       if (r0 >= count) r0 = count - 1;
    int r1 = mt * 256 + (q0 + 1) * 64 + lane; if (r1 >= count) r1 = count - 1;
    const unsigned short* ag0 = xg + (size_t)(base + r0) * H_DIM + kc * 8;
    const unsigned short* ag1 = xg + (size_t)(base + r1) * H_DIM + kc * 8;
    const int al0 = (kc * 256 + q0 * 64) * 8;
    const int al1 = (kc * 256 + (q0 + 1) * 64) * 8;

    // B staging mapping (bank-conflict-free): half(g/u), k-pair kb, cols {n1,+16,+32,+48}
    const int half = tid >> 8;
    const int t8   = tid & 255;
    const int kb   = (t8 >> 4) * 2;
    const int n1   = t8 & 15;
    const int kcb  = kb >> 3;
    const int k8   = kb & 7;
    const float* __restrict__ bsrc =
        gup_w + ((size_t)e * H_DIM + kb) * (2 * I_DIM) + (size_t)half * I_DIM + nt * 64 + n1;

    const int aoff = (lg * 256 + wm * 64 + l16) * 8;
    const int boff = (lg * 64 + wn * 32 + l16) * 8;

    float bq0[3][4], bq1[3][4];   // 3 prefetch sets, statically indexed only
    f32x4 accg[4][2], accu[4][2];
#pragma unroll
    for (int i = 0; i < 4; ++i)
#pragma unroll
        for (int f = 0; f < 2; ++f) { accg[i][f] = {0.f,0.f,0.f,0.f}; accu[i][f] = {0.f,0.f,0.f,0.f}; }

#define GU_AISS(KV, AB) do { \
    gld16(ag0 + (size_t)(KV) * 32, &As[AB][al0]); \
    gld16(ag1 + (size_t)(KV) * 32, &As[AB][al1]); } while (0)
#define GU_BLOAD(KV, S) do { \
    const float* bs_ = bsrc + (size_t)(KV) * 32 * (2 * I_DIM); \
    _Pragma("unroll") for (int j = 0; j < 4; ++j) { \
        bq0[S][j] = bs_[j * 16]; bq1[S][j] = bs_[2 * I_DIM + j * 16]; } } while (0)
#define GU_BWRITE(S) do { \
    unsigned short* bw_ = half ? &Bu[S][0] : &Bg[S][0]; \
    _Pragma("unroll") for (int j = 0; j < 4; ++j) \
        *(unsigned*)&bw_[(kcb * 64 + n1 + 16 * j) * 8 + k8] = pk2(bq0[S][j], bq1[S][j]); } while (0)
#define GU_COMP(RA, PH) do { \
    const unsigned short* af_ = &As[RA][aoff]; \
    const unsigned short* bg_ = &Bg[PH][boff]; \
    const unsigned short* bu_ = &Bu[PH][boff]; \
    bf16x8 vb0 = *(const bf16x8*)(bg_); \
    bf16x8 vb1 = *(const bf16x8*)(bg_ + 128); \
    bf16x8 vb2 = *(const bf16x8*)(bu_); \
    bf16x8 vb3 = *(const bf16x8*)(bu_ + 128); \
    __builtin_amdgcn_s_setprio(1); \
    _Pragma("unroll") for (int i = 0; i < 4; ++i) { \
        bf16x8 va = *(const bf16x8*)(af_ + i * 128); \
        accg[i][0] = __builtin_amdgcn_mfma_f32_16x16x32_bf16(va, vb0, accg[i][0], 0, 0, 0); \
        accg[i][1] = __builtin_amdgcn_mfma_f32_16x16x32_bf16(va, vb1, accg[i][1], 0, 0, 0); \
        accu[i][0] = __builtin_amdgcn_mfma_f32_16x16x32_bf16(va, vb2, accu[i][0], 0, 0, 0); \
        accu[i][1] = __builtin_amdgcn_mfma_f32_16x16x32_bf16(va, vb3, accu[i][1], 0, 0, 0); } \
    __builtin_amdgcn_s_setprio(0); } while (0)
#define GU_STEP(KV, RA, PA, PH3, W3, VM, DO_A, DO_B, DO_W) do { \
    WAITB(VM); \
    if (DO_A) GU_AISS((KV) + 1, PA); \
    SB0(); \
    if (DO_B) GU_BLOAD((KV) + 3, PH3); \
    SB0(); \
    if (DO_W) GU_BWRITE(W3); \
    GU_COMP(RA, PH3); } while (0)

    // prologue: issue order [A(0)x2, B0x8, B1x8, B2x8], then write B0
    GU_AISS(0, 0);  SB0();
    GU_BLOAD(0, 0); SB0();
    GU_BLOAD(1, 1); SB0();
    GU_BLOAD(2, 2); SB0();
    GU_BWRITE(0);

    GU_STEP(0, 0, 1, 0, 1, 24, 1, 1, 1);
    GU_STEP(1, 1, 0, 1, 2,  8, 1, 1, 1);
    for (int k6 = 2; k6 < 56; k6 += 6) {
        GU_STEP(k6 + 0, 0, 1, 2, 0, 8, 1, 1, 1);
        GU_STEP(k6 + 1, 1, 0, 0, 1, 8, 1, 1, 1);
        GU_STEP(k6 + 2, 0, 1, 1, 2, 8, 1, 1, 1);
        GU_STEP(k6 + 3, 1, 0, 2, 0, 8, 1, 1, 1);
        GU_STEP(k6 + 4, 0, 1, 0, 1, 8, 1, 1, 1);
        GU_STEP(k6 + 5, 1, 0, 1, 2, 8, 1, 1, 1);
    }
    // steps 56..61 (last legal BLOAD is KV=63 at step 60; step 61 must not load)
    GU_STEP(56, 0, 1, 2, 0, 8, 1, 1, 1);
    GU_STEP(57, 1, 0, 0, 1, 8, 1, 1, 1);
    GU_STEP(58, 0, 1, 1, 2, 8, 1, 1, 1);
    GU_STEP(59, 1, 0, 2, 0, 8, 1, 1, 1);
    GU_STEP(60, 0, 1, 0, 1, 8, 1, 1, 1);
    GU_STEP(61, 1, 0, 1, 2, 8, 1, 0, 1);
    GU_STEP(62, 0, 1, 2, 0, 0, 1, 0, 1);
    GU_STEP(63, 1, 0, 0, 1, 0, 0, 0, 0);

#undef GU_AISS
#undef GU_BLOAD
#undef GU_BWRITE
#undef GU_COMP
#undef GU_STEP

#pragma unroll
    for (int i = 0; i < 4; ++i) {
        const int mloc = wm * 64 + i * 16 + lg * 4;
#pragma unroll
        for (int r = 0; r < 4; ++r) {
            const int mrow = mt * 256 + mloc + r;
            if (mrow < count) {
                const float wgt = wls[mloc + r];
#pragma unroll
                for (int f = 0; f < 2; ++f) {
                    const int col = nt * 64 + wn * 32 + f * 16 + l16;
                    float g = accg[i][f][r], u = accu[i][f][r];
                    float sv = g / (1.f + expf(-g));
                    __hip_bfloat16 hb = __float2bfloat16(wgt * u * sv);
                    h_buf[(size_t)(base + mrow) * I_DIM + col] = *(unsigned short*)&hb;
                }
            }
        }
    }
}

// ---------------- down MFMA -> atomic accumulate into out ----------------
// tile 256(M) x 128(N), BK=32, 8 waves; same counted-vmcnt pipeline, NT=24.
__global__ __launch_bounds__(512, 2) void down_mfma(
    const unsigned short* __restrict__ h_buf, const float* __restrict__ down_w,
    const int* __restrict__ cnt, const int* __restrict__ slot_base,
    const int* __restrict__ tok_list, float* __restrict__ out)
{
    const int e  = blockIdx.z;
    const int mt = blockIdx.y;
    const int nt = blockIdx.x;
    const int count = cnt[e];
    if (mt * 256 >= count) return;
    const int tid  = threadIdx.x;
    const int lane = tid & 63;
    const int w    = tid >> 6;
    const int wm   = w >> 1;
    const int wn   = w & 1;
    const int base = slot_base[e];
    const int l16  = lane & 15, lg = lane >> 4;

    __shared__ unsigned short As[2][4 * 256 * 8];   // 32 KB
    __shared__ unsigned short Bs[3][4 * 128 * 8];   // 24 KB
    __shared__ int toks[256];                       //  1 KB

    if (tid < 256) {
        int m = mt * 256 + tid; if (m >= count) m = count - 1;
        toks[tid] = tok_list[e * T_TOK + m];
    }
    asm volatile("s_waitcnt vmcnt(0) lgkmcnt(0)" ::: "memory");
    SB0();

    const int kc = w >> 1;
    const int q0 = (w & 1) * 2;
    int r0 = mt * 256 + q0 * 64 + lane;       if (r0 >= count) r0 = count - 1;
    int r1 = mt * 256 + (q0 + 1) * 64 + lane; if (r1 >= count) r1 = count - 1;
    const unsigned short* ag0 = h_buf + (size_t)(base + r0) * I_DIM + kc * 8;
    const unsigned short* ag1 = h_buf + (size_t)(base + r1) * I_DIM + kc * 8;
    const int al0 = (kc * 256 + q0 * 64) * 8;
    const int al1 = (kc * 256 + (q0 + 1) * 64) * 8;

    const int kb  = (tid >> 5) * 2;
    const int n1  = tid & 31;
    const int kcb = kb >> 3;
    const int k8  = kb & 7;
    const float* __restrict__ bsrc =
        down_w + ((size_t)e * I_DIM + kb) * H_DIM + nt * 128 + n1;

    const int aoff = (lg * 256 + wm * 64 + l16) * 8;
    const int boff = (lg * 128 + wn * 64 + l16) * 8;

    float bq0[3][4], bq1[3][4];
    f32x4 acc[4][4];
#pragma unroll
    for (int i = 0; i < 4; ++i)
#pragma unroll
        for (int f = 0; f < 4; ++f) acc[i][f] = {0.f,0.f,0.f,0.f};

#define DN_AISS(KV, AB) do { \
    gld16(ag0 + (size_t)(KV) * 32, &As[AB][al0]); \
    gld16(ag1 + (size_t)(KV) * 32, &As[AB][al1]); } while (0)
#define DN_BLOAD(KV, S) do { \
    const float* bs_ = bsrc + (size_t)(KV) * 32 * H_DIM; \
    _Pragma("unroll") for (int j = 0; j < 4; ++j) { \
        bq0[S][j] = bs_[j * 32]; bq1[S][j] = bs_[H_DIM + j * 32]; } } while (0)
#define DN_BWRITE(S) do { \
    unsigned short* bw_ = &Bs[S][0]; \
    _Pragma("unroll") for (int j = 0; j < 4; ++j) \
        *(unsigned*)&bw_[(kcb * 128 + n1 + 32 * j) * 8 + k8] = pk2(bq0[S][j], bq1[S][j]); } while (0)
#define DN_COMP(RA, PH) do { \
    const unsigned short* af_ = &As[RA][aoff]; \
    const unsigned short* bf_ = &Bs[PH][boff]; \
    bf16x8 vb0 = *(const bf16x8*)(bf_); \
    bf16x8 vb1 = *(const bf16x8*)(bf_ + 128); \
    bf16x8 vb2 = *(const bf16x8*)(bf_ + 256); \
    bf16x8 vb3 = *(const bf16x8*)(bf_ + 384); \
    __builtin_amdgcn_s_setprio(1); \
    _Pragma("unroll") for (int i = 0; i < 4; ++i) { \
        bf16x8 va = *(const bf16x8*)(af_ + i * 128); \
        acc[i][0] = __builtin_amdgcn_mfma_f32_16x16x32_bf16(va, vb0, acc[i][0], 0, 0, 0); \
        acc[i][1] = __builtin_amdgcn_mfma_f32_16x16x32_bf16(va, vb1, acc[i][1], 0, 0, 0); \
        acc[i][2] = __builtin_amdgcn_mfma_f32_16x16x32_bf16(va, vb2, acc[i][2], 0, 0, 0); \
        acc[i][3] = __builtin_amdgcn_mfma_f32_16x16x32_bf16(va, vb3, acc[i][3], 0, 0, 0); } \
    __builtin_amdgcn_s_setprio(0); } while (0)
#define DN_STEP(KV, RA, PA, PH3, W3, VM, DO_A, DO_B, DO_W) do { \
    WAITB(VM); \
    if (DO_A) DN_AISS((KV) + 1, PA); \
    SB0(); \
    if (DO_B) DN_BLOAD((KV) + 3, PH3); \
    SB0(); \
    if (DO_W) DN_BWRITE(W3); \
    DN_COMP(RA, PH3); } while (0)

    DN_AISS(0, 0);  SB0();
    DN_BLOAD(0, 0); SB0();
    DN_BLOAD(1, 1); SB0();
    DN_BLOAD(2, 2); SB0();
    DN_BWRITE(0);

    DN_STEP(0, 0, 1, 0, 1, 24, 1, 1, 1);
    DN_STEP(1, 1, 0, 1, 2,  8, 1, 1, 1);
    for (int k6 = 2; k6 < 20; k6 += 6) {
        DN_STEP(k6 + 0, 0, 1, 2, 0, 8, 1, 1, 1);
        DN_STEP(k6 + 1, 1, 0, 0, 1, 8, 1, 1, 1);
        DN_STEP(k6 + 2, 0, 1, 1, 2, 8, 1, 1, 1);
        DN_STEP(k6 + 3, 1, 0, 2, 0, 8, 1, 1, 1);
        DN_STEP(k6 + 4, 0, 1, 0, 1, 8, 1, 1, 1);
        DN_STEP(k6 + 5, 1, 0, 1, 2, 8, 1, 1, 1);
    }
    DN_STEP(20, 0, 1, 2, 0, 8, 1, 1, 1);
    DN_STEP(21, 1, 0, 0, 1, 8, 1, 0, 1);
    DN_STEP(22, 0, 1, 1, 2, 0, 1, 0, 1);
    DN_STEP(23, 1, 0, 2, 0, 0, 0, 0, 0);

#undef DN_AISS
#undef DN_BLOAD
#undef DN_BWRITE
#undef DN_COMP
#undef DN_STEP

#pragma unroll
    for (int i = 0; i < 4; ++i) {
        const int mloc = wm * 64 + i * 16 + lg * 4;
#pragma unroll
        for (int r = 0; r < 4; ++r) {
            const int mrow = mt * 256 + mloc + r;
            if (mrow < count) {
                const int tok = toks[mloc + r];
#pragma unroll
                for (int f = 0; f < 4; ++f) {
                    const int col = nt * 128 + wn * 64 + f * 16 + l16;
                    atomicAdd(&out[(size_t)tok * H_DIM + col], acc[i][f][r]);
                }
            }
        }
    }
}

extern "C" void kernel_launch(void* const* d_in, const int* in_sizes, int n_in,
                              void* d_out, int out_size, void* d_ws, size_t ws_size,
                              hipStream_t stream) {
    const float* x      = (const float*)d_in[0];
    const float* gate_w = (const float*)d_in[1];
    const float* gup_w  = (const float*)d_in[2];
    const float* down_w = (const float*)d_in[3];
    float* out    = (float*)d_out;

    char* wsp = (char*)d_ws;
    int*   cnt       = (int*)(wsp);
    int*   slot_base = (int*)(wsp + 256);
    int*   tok_list  = (int*)(wsp + 4096);
    float* tok_w     = (float*)(wsp + 4096 + (size_t)E_NUM * T_TOK * 4);
    unsigned short* xg    = (unsigned short*)(wsp + (1u << 20));
    unsigned short* h_buf = (unsigned short*)(wsp + (1u << 20) + (size_t)T_TOK * TOPK * H_DIM * 2);

    hipMemsetAsync(out, 0, (size_t)T_TOK * H_DIM * sizeof(float), stream);
    hipMemsetAsync(cnt, 0, 256, stream);

    router_kernel<<<T_TOK, 64, 0, stream>>>(x, gate_w, out + (size_t)T_TOK * H_DIM,
                                            cnt, tok_list, tok_w);
    scan_kernel<<<1, 64, 0, stream>>>(cnt, slot_base);
    gather_kernel<<<dim3(128, 32), 256, 0, stream>>>(x, cnt, slot_base, tok_list, xg);
    gateup_mfma<<<dim3(I_DIM / 64, 8, E_NUM), 512, 0, stream>>>(
        xg, gup_w, cnt, slot_base, tok_w, h_buf);
    down_mfma<<<dim3(H_DIM / 128, 8, E_NUM), 512, 0, stream>>>(
        h_buf, down_w, cnt, slot_base, tok_list, out);
}

// Round 6
// 679.055 us; speedup vs baseline: 1.0542x; 1.0542x over previous
//
#include <hip/hip_runtime.h>
#include <hip/hip_bf16.h>

#define T_TOK 2048
#define H_DIM 2048
#define E_NUM 32
#define I_DIM 768
#define TOPK  4

typedef __attribute__((ext_vector_type(8))) short bf16x8;
typedef __attribute__((ext_vector_type(4))) float f32x4;

__device__ __forceinline__ unsigned pk2(float a, float b) {
    __hip_bfloat16 ha = __float2bfloat16(a);
    __hip_bfloat16 hb = __float2bfloat16(b);
    unsigned short ua = *(unsigned short*)&ha;
    unsigned short ub = *(unsigned short*)&hb;
    return (unsigned)ua | ((unsigned)ub << 16);
}

__device__ __forceinline__ void gld16(const void* g, void* l) {
    __builtin_amdgcn_global_load_lds(
        (const __attribute__((address_space(1))) void*)g,
        (__attribute__((address_space(3))) void*)l, 16, 0, 0);
}

// ---------------- Router ----------------
__global__ __launch_bounds__(64) void router_kernel(
    const float* __restrict__ x, const float* __restrict__ gate_w,
    float* __restrict__ logits_out, int* __restrict__ cnt,
    int* __restrict__ tok_list, float* __restrict__ tok_w)
{
    const int t = blockIdx.x;
    const int lane = threadIdx.x;
    __shared__ float xs[H_DIM];
    const float4* __restrict__ xv = (const float4*)(x + (size_t)t * H_DIM);
    float4* xsv = (float4*)xs;
#pragma unroll
    for (int i = 0; i < H_DIM / 4 / 64; ++i) xsv[lane + i * 64] = xv[lane + i * 64];
    __syncthreads();

    const int e = lane & 31;
    const int half = lane >> 5;
    const float4* __restrict__ wv = (const float4*)(gate_w + (size_t)e * H_DIM) + half * (H_DIM / 8);
    const float4* __restrict__ xh = ((const float4*)xs) + half * (H_DIM / 8);
    float acc = 0.f;
#pragma unroll 4
    for (int i = 0; i < H_DIM / 8; ++i) {
        float4 w4 = wv[i], x4 = xh[i];
        acc += w4.x * x4.x + w4.y * x4.y + w4.z * x4.z + w4.w * x4.w;
    }
    acc += __shfl_xor(acc, 32, 64);
    if (lane < 32) logits_out[(size_t)t * E_NUM + e] = acc;

    float v = acc;
    float topv[TOPK]; int topi[TOPK];
#pragma unroll
    for (int r = 0; r < TOPK; ++r) {
        float bv = v; int bi = e;
#pragma unroll
        for (int off = 16; off >= 1; off >>= 1) {
            float ov = __shfl_xor(bv, off, 32);
            int   oi = __shfl_xor(bi, off, 32);
            if (ov > bv || (ov == bv && oi < bi)) { bv = ov; bi = oi; }
        }
        topv[r] = bv; topi[r] = bi;
        if (e == bi) v = -1e30f;
    }
    if (lane == 0) {
        float w[TOPK]; float s = 0.f;
#pragma unroll
        for (int r = 0; r < TOPK; ++r) { w[r] = expf(topv[r] - topv[0]); s += w[r]; }
        float inv = 1.f / s;
#pragma unroll
        for (int r = 0; r < TOPK; ++r) {
            int pos = atomicAdd(&cnt[topi[r]], 1);
            tok_list[topi[r] * T_TOK + pos] = t;
            tok_w  [topi[r] * T_TOK + pos] = w[r] * inv;
        }
    }
}

__global__ void scan_kernel(const int* __restrict__ cnt, int* __restrict__ slot_base)
{
    if (threadIdx.x == 0) {
        int s = 0;
        for (int e = 0; e < E_NUM; ++e) { slot_base[e] = s; s += cnt[e]; }
        slot_base[E_NUM] = s;
    }
}

// ---------------- Gather tokens per expert, convert x -> bf16 ----------------
__global__ __launch_bounds__(256) void gather_kernel(
    const float* __restrict__ x, const int* __restrict__ cnt,
    const int* __restrict__ slot_base, const int* __restrict__ tok_list,
    unsigned short* __restrict__ xg)
{
    const int e = blockIdx.y;
    const int count = cnt[e];
    const int m0 = blockIdx.x * 16;
    if (m0 >= count) return;
    const int r = threadIdx.x >> 4;
    const int m = m0 + r;
    if (m >= count) return;
    const int tok  = tok_list[e * T_TOK + m];
    const int slot = slot_base[e] + m;
    const float* __restrict__ src = x + (size_t)tok * H_DIM;
    unsigned short* __restrict__ dst = xg + (size_t)slot * H_DIM;
    for (int c = (threadIdx.x & 15) * 4; c < H_DIM; c += 64) {
        float4 v = *(const float4*)(src + c);
        *(unsigned*)(dst + c)     = pk2(v.x, v.y);
        *(unsigned*)(dst + c + 2) = pk2(v.z, v.w);
    }
}

// ---------------- gate_up MFMA + silu + weight-scale -> h (bf16) ----------------
// tile 256(M) x (32 gate + 32 up), BK=32, 8 waves, dbuf + 1 syncthreads/step.
// grid (24, 8, 32). LDS 41KB -> 3 blocks/CU (24 waves/CU).
#define GU_NT (H_DIM / 32)
__global__ __launch_bounds__(512, 6) void gateup_mfma(
    const unsigned short* __restrict__ xg, const float* __restrict__ gup_w,
    const int* __restrict__ cnt, const int* __restrict__ slot_base,
    const float* __restrict__ tok_w, unsigned short* __restrict__ h_buf)
{
    const int e  = blockIdx.z;
    const int mt = blockIdx.y;
    const int nt = blockIdx.x;
    const int count = cnt[e];
    if (mt * 256 >= count) return;
    const int tid  = threadIdx.x;
    const int lane = tid & 63;
    const int w    = tid >> 6;        // 0..7, wave owns rows w*32..w*32+31
    const int base = slot_base[e];
    const int l16  = lane & 15, lg = lane >> 4;

    __shared__ unsigned short As[2][4 * 256 * 8];   // 32 KB  [kc][m][8]
    __shared__ unsigned short Bg[2][4 * 32 * 8];    //  4 KB  [kc][n][8]
    __shared__ unsigned short Bu[2][4 * 32 * 8];    //  4 KB
    __shared__ float wls[256];                      //  1 KB

    if (tid < 256) {
        int m = mt * 256 + tid; if (m >= count) m = count - 1;
        wls[tid] = tok_w[e * T_TOK + m];
    }

    // ---- A staging (gld16): wave -> kc = w>>1, two 64-row bands
    const int kc = w >> 1;
    const int q0 = (w & 1) * 2;
    int r0 = mt * 256 + q0 * 64 + lane;       if (r0 >= count) r0 = count - 1;
    int r1 = mt * 256 + (q0 + 1) * 64 + lane; if (r1 >= count) r1 = count - 1;
    const unsigned short* ag0 = xg + (size_t)(base + r0) * H_DIM + kc * 8;
    const unsigned short* ag1 = xg + (size_t)(base + r1) * H_DIM + kc * 8;
    const int al0 = (kc * 256 + q0 * 64) * 8;
    const int al1 = (kc * 256 + (q0 + 1) * 64) * 8;

    // ---- B staging: 256 threads; half=gate/up, k-pair kb, 4 cols n4 (float4)
    const bool bstage = tid < 256;
    const int bhalf = (tid >> 7) & 1;
    const int t7    = tid & 127;
    const int kb    = (t7 >> 3) * 2;     // 0,2,..,30
    const int n4    = (t7 & 7) * 4;      // 0..28
    const int kcb   = kb >> 3;
    const int k8    = kb & 7;
    const float* __restrict__ bsrc =
        gup_w + ((size_t)e * H_DIM + kb) * (2 * I_DIM) + (size_t)bhalf * I_DIM + nt * 32 + n4;

    const int aoff = (lg * 256 + w * 32 + l16) * 8;
    const int boff = (lg * 32 + l16) * 8;

    f32x4 accg[2][2], accu[2][2];
#pragma unroll
    for (int i = 0; i < 2; ++i)
#pragma unroll
        for (int f = 0; f < 2; ++f) { accg[i][f] = {0.f,0.f,0.f,0.f}; accu[i][f] = {0.f,0.f,0.f,0.f}; }

    float4 pr0, pr1;

    // prologue: stage ks=0 into buf 0
    gld16(ag0, &As[0][al0]);
    gld16(ag1, &As[0][al1]);
    if (bstage) {
        pr0 = *(const float4*)bsrc;
        pr1 = *(const float4*)(bsrc + 2 * I_DIM);
        unsigned short* bw = bhalf ? &Bu[0][0] : &Bg[0][0];
        float p0[4] = {pr0.x, pr0.y, pr0.z, pr0.w};
        float p1[4] = {pr1.x, pr1.y, pr1.z, pr1.w};
#pragma unroll
        for (int j = 0; j < 4; ++j)
            *(unsigned*)&bw[((kcb * 32 + n4 + j) * 8) + k8] = pk2(p0[j], p1[j]);
    }

    for (int ks = 0; ks < GU_NT; ++ks) {
        const int cur = ks & 1;
        __syncthreads();
        if (ks + 1 < GU_NT) {
            gld16(ag0 + (size_t)(ks + 1) * 32, &As[cur ^ 1][al0]);
            gld16(ag1 + (size_t)(ks + 1) * 32, &As[cur ^ 1][al1]);
            if (bstage) {
                const float* bs_ = bsrc + (size_t)(ks + 1) * 32 * (2 * I_DIM);
                pr0 = *(const float4*)bs_;
                pr1 = *(const float4*)(bs_ + 2 * I_DIM);
            }
        }
        // compute on buf[cur]
        {
            const unsigned short* af_ = &As[cur][aoff];
            const unsigned short* bg_ = &Bg[cur][boff];
            const unsigned short* bu_ = &Bu[cur][boff];
            bf16x8 vg0 = *(const bf16x8*)(bg_);
            bf16x8 vg1 = *(const bf16x8*)(bg_ + 128);
            bf16x8 vu0 = *(const bf16x8*)(bu_);
            bf16x8 vu1 = *(const bf16x8*)(bu_ + 128);
#pragma unroll
            for (int i = 0; i < 2; ++i) {
                bf16x8 va = *(const bf16x8*)(af_ + i * 16 * 8);
                accg[i][0] = __builtin_amdgcn_mfma_f32_16x16x32_bf16(va, vg0, accg[i][0], 0, 0, 0);
                accg[i][1] = __builtin_amdgcn_mfma_f32_16x16x32_bf16(va, vg1, accg[i][1], 0, 0, 0);
                accu[i][0] = __builtin_amdgcn_mfma_f32_16x16x32_bf16(va, vu0, accu[i][0], 0, 0, 0);
                accu[i][1] = __builtin_amdgcn_mfma_f32_16x16x32_bf16(va, vu1, accu[i][1], 0, 0, 0);
            }
        }
        if (ks + 1 < GU_NT && bstage) {
            unsigned short* bw = bhalf ? &Bu[cur ^ 1][0] : &Bg[cur ^ 1][0];
            float p0[4] = {pr0.x, pr0.y, pr0.z, pr0.w};
            float p1[4] = {pr1.x, pr1.y, pr1.z, pr1.w};
#pragma unroll
            for (int j = 0; j < 4; ++j)
                *(unsigned*)&bw[((kcb * 32 + n4 + j) * 8) + k8] = pk2(p0[j], p1[j]);
        }
    }

#pragma unroll
    for (int i = 0; i < 2; ++i) {
        const int mloc = w * 32 + i * 16 + lg * 4;
#pragma unroll
        for (int r = 0; r < 4; ++r) {
            const int mrow = mt * 256 + mloc + r;
            if (mrow < count) {
                const float wgt = wls[mloc + r];
#pragma unroll
                for (int f = 0; f < 2; ++f) {
                    const int col = nt * 32 + f * 16 + l16;
                    float g = accg[i][f][r], u = accu[i][f][r];
                    float sv = g / (1.f + expf(-g));
                    __hip_bfloat16 hb = __float2bfloat16(wgt * u * sv);
                    h_buf[(size_t)(base + mrow) * I_DIM + col] = *(unsigned short*)&hb;
                }
            }
        }
    }
}

// ---------------- down MFMA -> atomic accumulate into out ----------------
// tile 256(M) x 64(N), BK=32, 8 waves, dbuf + 1 syncthreads/step.
// grid (32, 8, 32). LDS 41KB -> 3 blocks/CU.
#define DN_NT (I_DIM / 32)
__global__ __launch_bounds__(512, 6) void down_mfma(
    const unsigned short* __restrict__ h_buf, const float* __restrict__ down_w,
    const int* __restrict__ cnt, const int* __restrict__ slot_base,
    const int* __restrict__ tok_list, float* __restrict__ out)
{
    const int e  = blockIdx.z;
    const int mt = blockIdx.y;
    const int nt = blockIdx.x;
    const int count = cnt[e];
    if (mt * 256 >= count) return;
    const int tid  = threadIdx.x;
    const int lane = tid & 63;
    const int w    = tid >> 6;
    const int base = slot_base[e];
    const int l16  = lane & 15, lg = lane >> 4;

    __shared__ unsigned short As[2][4 * 256 * 8];   // 32 KB
    __shared__ unsigned short Bs[2][4 * 64 * 8];    //  8 KB
    __shared__ int toks[256];                       //  1 KB

    if (tid < 256) {
        int m = mt * 256 + tid; if (m >= count) m = count - 1;
        toks[tid] = tok_list[e * T_TOK + m];
    }

    const int kc = w >> 1;
    const int q0 = (w & 1) * 2;
    int r0 = mt * 256 + q0 * 64 + lane;       if (r0 >= count) r0 = count - 1;
    int r1 = mt * 256 + (q0 + 1) * 64 + lane; if (r1 >= count) r1 = count - 1;
    const unsigned short* ag0 = h_buf + (size_t)(base + r0) * I_DIM + kc * 8;
    const unsigned short* ag1 = h_buf + (size_t)(base + r1) * I_DIM + kc * 8;
    const int al0 = (kc * 256 + q0 * 64) * 8;
    const int al1 = (kc * 256 + (q0 + 1) * 64) * 8;

    // B staging: 256 threads, k-pair kb, 4 cols n4 of 64
    const bool bstage = tid < 256;
    const int t8  = tid & 255;
    const int kb  = (t8 >> 4) * 2;    // 0..30
    const int n4  = (t8 & 15) * 4;    // 0..60
    const int kcb = kb >> 3;
    const int k8  = kb & 7;
    const float* __restrict__ bsrc =
        down_w + ((size_t)e * I_DIM + kb) * H_DIM + nt * 64 + n4;

    const int aoff = (lg * 256 + w * 32 + l16) * 8;
    const int boff = (lg * 64 + l16) * 8;

    f32x4 acc[2][4];
#pragma unroll
    for (int i = 0; i < 2; ++i)
#pragma unroll
        for (int f = 0; f < 4; ++f) acc[i][f] = {0.f,0.f,0.f,0.f};

    float4 pr0, pr1;

    gld16(ag0, &As[0][al0]);
    gld16(ag1, &As[0][al1]);
    if (bstage) {
        pr0 = *(const float4*)bsrc;
        pr1 = *(const float4*)(bsrc + H_DIM);
        float p0[4] = {pr0.x, pr0.y, pr0.z, pr0.w};
        float p1[4] = {pr1.x, pr1.y, pr1.z, pr1.w};
#pragma unroll
        for (int j = 0; j < 4; ++j)
            *(unsigned*)&Bs[0][((kcb * 64 + n4 + j) * 8) + k8] = pk2(p0[j], p1[j]);
    }

    for (int ks = 0; ks < DN_NT; ++ks) {
        const int cur = ks & 1;
        __syncthreads();
        if (ks + 1 < DN_NT) {
            gld16(ag0 + (size_t)(ks + 1) * 32, &As[cur ^ 1][al0]);
            gld16(ag1 + (size_t)(ks + 1) * 32, &As[cur ^ 1][al1]);
            if (bstage) {
                const float* bs_ = bsrc + (size_t)(ks + 1) * 32 * H_DIM;
                pr0 = *(const float4*)bs_;
                pr1 = *(const float4*)(bs_ + H_DIM);
            }
        }
        {
            const unsigned short* af_ = &As[cur][aoff];
            const unsigned short* bf_ = &Bs[cur][boff];
            bf16x8 vb0 = *(const bf16x8*)(bf_);
            bf16x8 vb1 = *(const bf16x8*)(bf_ + 128);
            bf16x8 vb2 = *(const bf16x8*)(bf_ + 256);
            bf16x8 vb3 = *(const bf16x8*)(bf_ + 384);
#pragma unroll
            for (int i = 0; i < 2; ++i) {
                bf16x8 va = *(const bf16x8*)(af_ + i * 16 * 8);
                acc[i][0] = __builtin_amdgcn_mfma_f32_16x16x32_bf16(va, vb0, acc[i][0], 0, 0, 0);
                acc[i][1] = __builtin_amdgcn_mfma_f32_16x16x32_bf16(va, vb1, acc[i][1], 0, 0, 0);
                acc[i][2] = __builtin_amdgcn_mfma_f32_16x16x32_bf16(va, vb2, acc[i][2], 0, 0, 0);
                acc[i][3] = __builtin_amdgcn_mfma_f32_16x16x32_bf16(va, vb3, acc[i][3], 0, 0, 0);
            }
        }
        if (ks + 1 < DN_NT && bstage) {
            float p0[4] = {pr0.x, pr0.y, pr0.z, pr0.w};
            float p1[4] = {pr1.x, pr1.y, pr1.z, pr1.w};
#pragma unroll
            for (int j = 0; j < 4; ++j)
                *(unsigned*)&Bs[cur ^ 1][((kcb * 64 + n4 + j) * 8) + k8] = pk2(p0[j], p1[j]);
        }
    }

#pragma unroll
    for (int i = 0; i < 2; ++i) {
        const int mloc = w * 32 + i * 16 + lg * 4;
#pragma unroll
        for (int r = 0; r < 4; ++r) {
            const int mrow = mt * 256 + mloc + r;
            if (mrow < count) {
                const int tok = toks[mloc + r];
#pragma unroll
                for (int f = 0; f < 4; ++f) {
                    const int col = nt * 64 + f * 16 + l16;
                    atomicAdd(&out[(size_t)tok * H_DIM + col], acc[i][f][r]);
                }
            }
        }
    }
}

extern "C" void kernel_launch(void* const* d_in, const int* in_sizes, int n_in,
                              void* d_out, int out_size, void* d_ws, size_t ws_size,
                              hipStream_t stream) {
    const float* x      = (const float*)d_in[0];
    const float* gate_w = (const float*)d_in[1];
    const float* gup_w  = (const float*)d_in[2];
    const float* down_w = (const float*)d_in[3];
    float* out    = (float*)d_out;

    char* wsp = (char*)d_ws;
    int*   cnt       = (int*)(wsp);
    int*   slot_base = (int*)(wsp + 256);
    int*   tok_list  = (int*)(wsp + 4096);
    float* tok_w     = (float*)(wsp + 4096 + (size_t)E_NUM * T_TOK * 4);
    unsigned short* xg    = (unsigned short*)(wsp + (1u << 20));
    unsigned short* h_buf = (unsigned short*)(wsp + (1u << 20) + (size_t)T_TOK * TOPK * H_DIM * 2);

    hipMemsetAsync(out, 0, (size_t)T_TOK * H_DIM * sizeof(float), stream);
    hipMemsetAsync(cnt, 0, 256, stream);

    router_kernel<<<T_TOK, 64, 0, stream>>>(x, gate_w, out + (size_t)T_TOK * H_DIM,
                                            cnt, tok_list, tok_w);
    scan_kernel<<<1, 64, 0, stream>>>(cnt, slot_base);
    gather_kernel<<<dim3(128, 32), 256, 0, stream>>>(x, cnt, slot_base, tok_list, xg);
    gateup_mfma<<<dim3(24, 8, E_NUM), 512, 0, stream>>>(
        xg, gup_w, cnt, slot_base, tok_w, h_buf);
    down_mfma<<<dim3(32, 8, E_NUM), 512, 0, stream>>>(
        h_buf, down_w, cnt, slot_base, tok_list, out);
}

// Round 7
// 504.157 us; speedup vs baseline: 1.4200x; 1.3469x over previous
//
#include <hip/hip_runtime.h>
#include <hip/hip_bf16.h>

#define T_TOK 2048
#define H_DIM 2048
#define E_NUM 32
#define I_DIM 768
#define TOPK  4
#define S4    (T_TOK * TOPK)          // 8192 slots

typedef __attribute__((ext_vector_type(8))) short bf16x8;
typedef __attribute__((ext_vector_type(4))) float f32x4;

__device__ __forceinline__ unsigned pk2(float a, float b) {
    __hip_bfloat16 ha = __float2bfloat16(a);
    __hip_bfloat16 hb = __float2bfloat16(b);
    unsigned short ua = *(unsigned short*)&ha;
    unsigned short ub = *(unsigned short*)&hb;
    return (unsigned)ua | ((unsigned)ub << 16);
}

__device__ __forceinline__ void gld16(const void* g, void* l) {
    __builtin_amdgcn_global_load_lds(
        (const __attribute__((address_space(1))) void*)g,
        (__attribute__((address_space(3))) void*)l, 16, 0, 0);
}

// ---------------- Router ----------------
__global__ __launch_bounds__(64) void router_kernel(
    const float* __restrict__ x, const float* __restrict__ gate_w,
    float* __restrict__ logits_out, int* __restrict__ cnt,
    int* __restrict__ tok_list, float* __restrict__ tok_w)
{
    const int t = blockIdx.x;
    const int lane = threadIdx.x;
    __shared__ float xs[H_DIM];
    const float4* __restrict__ xv = (const float4*)(x + (size_t)t * H_DIM);
    float4* xsv = (float4*)xs;
#pragma unroll
    for (int i = 0; i < H_DIM / 4 / 64; ++i) xsv[lane + i * 64] = xv[lane + i * 64];
    __syncthreads();

    const int e = lane & 31;
    const int half = lane >> 5;
    const float4* __restrict__ wv = (const float4*)(gate_w + (size_t)e * H_DIM) + half * (H_DIM / 8);
    const float4* __restrict__ xh = ((const float4*)xs) + half * (H_DIM / 8);
    float acc = 0.f;
#pragma unroll 4
    for (int i = 0; i < H_DIM / 8; ++i) {
        float4 w4 = wv[i], x4 = xh[i];
        acc += w4.x * x4.x + w4.y * x4.y + w4.z * x4.z + w4.w * x4.w;
    }
    acc += __shfl_xor(acc, 32, 64);
    if (lane < 32) logits_out[(size_t)t * E_NUM + e] = acc;

    float v = acc;
    float topv[TOPK]; int topi[TOPK];
#pragma unroll
    for (int r = 0; r < TOPK; ++r) {
        float bv = v; int bi = e;
#pragma unroll
        for (int off = 16; off >= 1; off >>= 1) {
            float ov = __shfl_xor(bv, off, 32);
            int   oi = __shfl_xor(bi, off, 32);
            if (ov > bv || (ov == bv && oi < bi)) { bv = ov; bi = oi; }
        }
        topv[r] = bv; topi[r] = bi;
        if (e == bi) v = -1e30f;
    }
    if (lane == 0) {
        float w[TOPK]; float s = 0.f;
#pragma unroll
        for (int r = 0; r < TOPK; ++r) { w[r] = expf(topv[r] - topv[0]); s += w[r]; }
        float inv = 1.f / s;
#pragma unroll
        for (int r = 0; r < TOPK; ++r) {
            int pos = atomicAdd(&cnt[topi[r]], 1);
            tok_list[topi[r] * T_TOK + pos] = t;
            tok_w  [topi[r] * T_TOK + pos] = w[r] * inv;
        }
    }
}

__global__ void scan_kernel(const int* __restrict__ cnt, int* __restrict__ slot_base)
{
    if (threadIdx.x == 0) {
        int s = 0;
        for (int e = 0; e < E_NUM; ++e) { slot_base[e] = s; s += cnt[e]; }
        slot_base[E_NUM] = s;
    }
}

// ------- Gather tokens per expert, convert x -> bf16 in K-PANEL layout -------
// xg_t[kc][slot][8], kc in [0,256). Block 256 = 8 slots x 32 k-chunks.
// Reads: 32 lanes x 32B contiguous (1KB runs). Writes: 16B per (kc,slot).
__global__ __launch_bounds__(256) void gather_kernel(
    const float* __restrict__ x, const int* __restrict__ cnt,
    const int* __restrict__ slot_base, const int* __restrict__ tok_list,
    unsigned short* __restrict__ xg_t)
{
    const int e = blockIdx.y;
    const int count = cnt[e];
    const int m0 = blockIdx.x * 8;
    if (m0 >= count) return;
    const int s8   = threadIdx.x >> 5;   // 0..7
    const int kc31 = threadIdx.x & 31;
    const int m = m0 + s8;
    if (m >= count) return;
    const int tok  = tok_list[e * T_TOK + m];
    const int slot = slot_base[e] + m;
    const float* __restrict__ src = x + (size_t)tok * H_DIM;
#pragma unroll
    for (int kcq = 0; kcq < 8; ++kcq) {
        const int kc = kcq * 32 + kc31;
        float4 a = *(const float4*)(src + kc * 8);
        float4 b = *(const float4*)(src + kc * 8 + 4);
        uint4 o;
        o.x = pk2(a.x, a.y); o.y = pk2(a.z, a.w);
        o.z = pk2(b.x, b.y); o.w = pk2(b.z, b.w);
        *(uint4*)(xg_t + ((size_t)kc * S4 + slot) * 8) = o;
    }
}

// ---------------- gate_up MFMA + silu + weight-scale -> h_t (panel bf16) -----
// tile 256(M) x 32(h-cols: 32g+32u weights), BK=32, 8 waves, dbuf.
// A staged from panels: fully coalesced gld16. grid (24, 8, 32).
#define GU_NT (H_DIM / 32)
__global__ __launch_bounds__(512, 6) void gateup_mfma(
    const unsigned short* __restrict__ xg_t, const float* __restrict__ gup_w,
    const int* __restrict__ cnt, const int* __restrict__ slot_base,
    const float* __restrict__ tok_w, unsigned short* __restrict__ h_t)
{
    const int e  = blockIdx.z;
    const int mt = blockIdx.y;
    const int nt = blockIdx.x;
    const int count = cnt[e];
    if (mt * 256 >= count) return;
    const int tid  = threadIdx.x;
    const int lane = tid & 63;
    const int w    = tid >> 6;        // wave owns rows w*32..w*32+31
    const int base = slot_base[e];
    const int l16  = lane & 15, lg = lane >> 4;

    __shared__ unsigned short As[2][4 * 256 * 8];   // 32 KB  [kc][m][8]
    __shared__ unsigned short Bg[2][4 * 32 * 8];    //  4 KB  [kc][n][8]
    __shared__ unsigned short Bu[2][4 * 32 * 8];    //  4 KB
    __shared__ float wls[256];                      //  1 KB

    if (tid < 256) {
        int m = mt * 256 + tid; if (m >= count) m = count - 1;
        wls[tid] = tok_w[e * T_TOK + m];
    }

    // ---- A staging from panels: wave -> kc = w>>1, two 64-row bands (coalesced)
    const int kc = w >> 1;
    const int q0 = (w & 1) * 2;
    int r0 = mt * 256 + q0 * 64 + lane;       if (r0 >= count) r0 = count - 1;
    int r1 = mt * 256 + (q0 + 1) * 64 + lane; if (r1 >= count) r1 = count - 1;
    const unsigned short* ag0 = xg_t + (size_t)kc * (S4 * 8) + (size_t)(base + r0) * 8;
    const unsigned short* ag1 = xg_t + (size_t)kc * (S4 * 8) + (size_t)(base + r1) * 8;
    const int al0 = (kc * 256 + q0 * 64) * 8;
    const int al1 = (kc * 256 + (q0 + 1) * 64) * 8;
    const size_t astep = (size_t)4 * S4 * 8;   // 4 panels per K-step

    // ---- B staging: 256 threads; half=gate/up, k-pair kb, 4 cols n4 (float4)
    const bool bstage = tid < 256;
    const int bhalf = (tid >> 7) & 1;
    const int t7    = tid & 127;
    const int kb    = (t7 >> 3) * 2;     // 0,2,..,30
    const int n4    = (t7 & 7) * 4;      // 0..28
    const int kcb   = kb >> 3;
    const int k8    = kb & 7;
    const float* __restrict__ bsrc =
        gup_w + ((size_t)e * H_DIM + kb) * (2 * I_DIM) + (size_t)bhalf * I_DIM + nt * 32 + n4;

    const int aoff = (lg * 256 + w * 32 + l16) * 8;
    const int boff = (lg * 32 + l16) * 8;

    f32x4 accg[2][2], accu[2][2];
#pragma unroll
    for (int i = 0; i < 2; ++i)
#pragma unroll
        for (int f = 0; f < 2; ++f) { accg[i][f] = {0.f,0.f,0.f,0.f}; accu[i][f] = {0.f,0.f,0.f,0.f}; }

    float4 pr0, pr1;

    gld16(ag0, &As[0][al0]);
    gld16(ag1, &As[0][al1]);
    if (bstage) {
        pr0 = *(const float4*)bsrc;
        pr1 = *(const float4*)(bsrc + 2 * I_DIM);
        unsigned short* bw = bhalf ? &Bu[0][0] : &Bg[0][0];
        float p0[4] = {pr0.x, pr0.y, pr0.z, pr0.w};
        float p1[4] = {pr1.x, pr1.y, pr1.z, pr1.w};
#pragma unroll
        for (int j = 0; j < 4; ++j)
            *(unsigned*)&bw[((kcb * 32 + n4 + j) * 8) + k8] = pk2(p0[j], p1[j]);
    }

    for (int ks = 0; ks < GU_NT; ++ks) {
        const int cur = ks & 1;
        __syncthreads();
        if (ks + 1 < GU_NT) {
            gld16(ag0 + (size_t)(ks + 1) * astep, &As[cur ^ 1][al0]);
            gld16(ag1 + (size_t)(ks + 1) * astep, &As[cur ^ 1][al1]);
            if (bstage) {
                const float* bs_ = bsrc + (size_t)(ks + 1) * 32 * (2 * I_DIM);
                pr0 = *(const float4*)bs_;
                pr1 = *(const float4*)(bs_ + 2 * I_DIM);
            }
        }
        {
            const unsigned short* af_ = &As[cur][aoff];
            const unsigned short* bg_ = &Bg[cur][boff];
            const unsigned short* bu_ = &Bu[cur][boff];
            bf16x8 vg0 = *(const bf16x8*)(bg_);
            bf16x8 vg1 = *(const bf16x8*)(bg_ + 128);
            bf16x8 vu0 = *(const bf16x8*)(bu_);
            bf16x8 vu1 = *(const bf16x8*)(bu_ + 128);
#pragma unroll
            for (int i = 0; i < 2; ++i) {
                bf16x8 va = *(const bf16x8*)(af_ + i * 16 * 8);
                accg[i][0] = __builtin_amdgcn_mfma_f32_16x16x32_bf16(va, vg0, accg[i][0], 0, 0, 0);
                accg[i][1] = __builtin_amdgcn_mfma_f32_16x16x32_bf16(va, vg1, accg[i][1], 0, 0, 0);
                accu[i][0] = __builtin_amdgcn_mfma_f32_16x16x32_bf16(va, vu0, accu[i][0], 0, 0, 0);
                accu[i][1] = __builtin_amdgcn_mfma_f32_16x16x32_bf16(va, vu1, accu[i][1], 0, 0, 0);
            }
        }
        if (ks + 1 < GU_NT && bstage) {
            unsigned short* bw = bhalf ? &Bu[cur ^ 1][0] : &Bg[cur ^ 1][0];
            float p0[4] = {pr0.x, pr0.y, pr0.z, pr0.w};
            float p1[4] = {pr1.x, pr1.y, pr1.z, pr1.w};
#pragma unroll
            for (int j = 0; j < 4; ++j)
                *(unsigned*)&bw[((kcb * 32 + n4 + j) * 8) + k8] = pk2(p0[j], p1[j]);
        }
    }

    // epilogue: silu(g)*u*wgt -> h_t panels [ic][slot][8]
#pragma unroll
    for (int i = 0; i < 2; ++i) {
        const int mloc = w * 32 + i * 16 + lg * 4;
#pragma unroll
        for (int r = 0; r < 4; ++r) {
            const int mrow = mt * 256 + mloc + r;
            if (mrow < count) {
                const float wgt = wls[mloc + r];
                const size_t slot = (size_t)(slot_base[e] + mrow);
#pragma unroll
                for (int f = 0; f < 2; ++f) {
                    const int col = nt * 32 + f * 16 + l16;
                    float g = accg[i][f][r], u = accu[i][f][r];
                    float sv = g / (1.f + expf(-g));
                    __hip_bfloat16 hb = __float2bfloat16(wgt * u * sv);
                    h_t[((size_t)(col >> 3) * S4 + slot) * 8 + (col & 7)] = *(unsigned short*)&hb;
                }
            }
        }
    }
}

// ---------------- down MFMA -> atomic accumulate into out ----------------
// tile 256(M) x 64(N), BK=32, 8 waves, dbuf; A from h_t panels. grid (32, 8, 32).
#define DN_NT (I_DIM / 32)
__global__ __launch_bounds__(512, 6) void down_mfma(
    const unsigned short* __restrict__ h_t, const float* __restrict__ down_w,
    const int* __restrict__ cnt, const int* __restrict__ slot_base,
    const int* __restrict__ tok_list, float* __restrict__ out)
{
    const int e  = blockIdx.z;
    const int mt = blockIdx.y;
    const int nt = blockIdx.x;
    const int count = cnt[e];
    if (mt * 256 >= count) return;
    const int tid  = threadIdx.x;
    const int lane = tid & 63;
    const int w    = tid >> 6;
    const int base = slot_base[e];
    const int l16  = lane & 15, lg = lane >> 4;

    __shared__ unsigned short As[2][4 * 256 * 8];   // 32 KB
    __shared__ unsigned short Bs[2][4 * 64 * 8];    //  8 KB
    __shared__ int toks[256];                       //  1 KB

    if (tid < 256) {
        int m = mt * 256 + tid; if (m >= count) m = count - 1;
        toks[tid] = tok_list[e * T_TOK + m];
    }

    const int kc = w >> 1;
    const int q0 = (w & 1) * 2;
    int r0 = mt * 256 + q0 * 64 + lane;       if (r0 >= count) r0 = count - 1;
    int r1 = mt * 256 + (q0 + 1) * 64 + lane; if (r1 >= count) r1 = count - 1;
    const unsigned short* ag0 = h_t + (size_t)kc * (S4 * 8) + (size_t)(base + r0) * 8;
    const unsigned short* ag1 = h_t + (size_t)kc * (S4 * 8) + (size_t)(base + r1) * 8;
    const int al0 = (kc * 256 + q0 * 64) * 8;
    const int al1 = (kc * 256 + (q0 + 1) * 64) * 8;
    const size_t astep = (size_t)4 * S4 * 8;

    const bool bstage = tid < 256;
    const int t8  = tid & 255;
    const int kb  = (t8 >> 4) * 2;    // 0..30
    const int n4  = (t8 & 15) * 4;    // 0..60
    const int kcb = kb >> 3;
    const int k8  = kb & 7;
    const float* __restrict__ bsrc =
        down_w + ((size_t)e * I_DIM + kb) * H_DIM + nt * 64 + n4;

    const int aoff = (lg * 256 + w * 32 + l16) * 8;
    const int boff = (lg * 64 + l16) * 8;

    f32x4 acc[2][4];
#pragma unroll
    for (int i = 0; i < 2; ++i)
#pragma unroll
        for (int f = 0; f < 4; ++f) acc[i][f] = {0.f,0.f,0.f,0.f};

    float4 pr0, pr1;

    gld16(ag0, &As[0][al0]);
    gld16(ag1, &As[0][al1]);
    if (bstage) {
        pr0 = *(const float4*)bsrc;
        pr1 = *(const float4*)(bsrc + H_DIM);
        float p0[4] = {pr0.x, pr0.y, pr0.z, pr0.w};
        float p1[4] = {pr1.x, pr1.y, pr1.z, pr1.w};
#pragma unroll
        for (int j = 0; j < 4; ++j)
            *(unsigned*)&Bs[0][((kcb * 64 + n4 + j) * 8) + k8] = pk2(p0[j], p1[j]);
    }

    for (int ks = 0; ks < DN_NT; ++ks) {
        const int cur = ks & 1;
        __syncthreads();
        if (ks + 1 < DN_NT) {
            gld16(ag0 + (size_t)(ks + 1) * astep, &As[cur ^ 1][al0]);
            gld16(ag1 + (size_t)(ks + 1) * astep, &As[cur ^ 1][al1]);
            if (bstage) {
                const float* bs_ = bsrc + (size_t)(ks + 1) * 32 * H_DIM;
                pr0 = *(const float4*)bs_;
                pr1 = *(const float4*)(bs_ + H_DIM);
            }
        }
        {
            const unsigned short* af_ = &As[cur][aoff];
            const unsigned short* bf_ = &Bs[cur][boff];
            bf16x8 vb0 = *(const bf16x8*)(bf_);
            bf16x8 vb1 = *(const bf16x8*)(bf_ + 128);
            bf16x8 vb2 = *(const bf16x8*)(bf_ + 256);
            bf16x8 vb3 = *(const bf16x8*)(bf_ + 384);
#pragma unroll
            for (int i = 0; i < 2; ++i) {
                bf16x8 va = *(const bf16x8*)(af_ + i * 16 * 8);
                acc[i][0] = __builtin_amdgcn_mfma_f32_16x16x32_bf16(va, vb0, acc[i][0], 0, 0, 0);
                acc[i][1] = __builtin_amdgcn_mfma_f32_16x16x32_bf16(va, vb1, acc[i][1], 0, 0, 0);
                acc[i][2] = __builtin_amdgcn_mfma_f32_16x16x32_bf16(va, vb2, acc[i][2], 0, 0, 0);
                acc[i][3] = __builtin_amdgcn_mfma_f32_16x16x32_bf16(va, vb3, acc[i][3], 0, 0, 0);
            }
        }
        if (ks + 1 < DN_NT && bstage) {
            float p0[4] = {pr0.x, pr0.y, pr0.z, pr0.w};
            float p1[4] = {pr1.x, pr1.y, pr1.z, pr1.w};
#pragma unroll
            for (int j = 0; j < 4; ++j)
                *(unsigned*)&Bs[cur ^ 1][((kcb * 64 + n4 + j) * 8) + k8] = pk2(p0[j], p1[j]);
        }
    }

#pragma unroll
    for (int i = 0; i < 2; ++i) {
        const int mloc = w * 32 + i * 16 + lg * 4;
#pragma unroll
        for (int r = 0; r < 4; ++r) {
            const int mrow = mt * 256 + mloc + r;
            if (mrow < count) {
                const int tok = toks[mloc + r];
#pragma unroll
                for (int f = 0; f < 4; ++f) {
                    const int col = nt * 64 + f * 16 + l16;
                    atomicAdd(&out[(size_t)tok * H_DIM + col], acc[i][f][r]);
                }
            }
        }
    }
}

extern "C" void kernel_launch(void* const* d_in, const int* in_sizes, int n_in,
                              void* d_out, int out_size, void* d_ws, size_t ws_size,
                              hipStream_t stream) {
    const float* x      = (const float*)d_in[0];
    const float* gate_w = (const float*)d_in[1];
    const float* gup_w  = (const float*)d_in[2];
    const float* down_w = (const float*)d_in[3];
    float* out    = (float*)d_out;

    char* wsp = (char*)d_ws;
    int*   cnt       = (int*)(wsp);
    int*   slot_base = (int*)(wsp + 256);
    int*   tok_list  = (int*)(wsp + 4096);
    float* tok_w     = (float*)(wsp + 4096 + (size_t)E_NUM * T_TOK * 4);
    unsigned short* xg_t = (unsigned short*)(wsp + (1u << 20));                          // 33.6 MB
    unsigned short* h_t  = (unsigned short*)(wsp + (1u << 20) + (size_t)S4 * H_DIM * 2); // 12.6 MB

    hipMemsetAsync(out, 0, (size_t)T_TOK * H_DIM * sizeof(float), stream);
    hipMemsetAsync(cnt, 0, 256, stream);

    router_kernel<<<T_TOK, 64, 0, stream>>>(x, gate_w, out + (size_t)T_TOK * H_DIM,
                                            cnt, tok_list, tok_w);
    scan_kernel<<<1, 64, 0, stream>>>(cnt, slot_base);
    gather_kernel<<<dim3(256, E_NUM), 256, 0, stream>>>(x, cnt, slot_base, tok_list, xg_t);
    gateup_mfma<<<dim3(24, 8, E_NUM), 512, 0, stream>>>(
        xg_t, gup_w, cnt, slot_base, tok_w, h_t);
    down_mfma<<<dim3(32, 8, E_NUM), 512, 0, stream>>>(
        h_t, down_w, cnt, slot_base, tok_list, out);
}